// Round 2
// baseline (367.477 us; speedup 1.0000x reference)
//
#include <hip/hip_runtime.h>
#include <hip/hip_bf16.h>

typedef __bf16 bf16_t;
typedef __attribute__((ext_vector_type(8))) __bf16 bf16x8;
typedef __attribute__((ext_vector_type(4))) __bf16 bf16x4;
typedef __attribute__((ext_vector_type(4))) float f32x4;

#define N1 16384
#define N2 4096
#define C1 128
#define C2 256
#define CIN 384
#define HD1 256
#define HD2 128
#define BDIM 4

// ---- prep: transpose + cast weights to bf16, and pack xyz2 -> [x,y,z,|p|^2] ----
__global__ void prep_w(const float* __restrict__ W1, const float* __restrict__ W2,
                       const float* __restrict__ xyz2,
                       bf16_t* __restrict__ W1t, bf16_t* __restrict__ W2t,
                       float4* __restrict__ xyzr) {
  int tid = blockIdx.x * 256 + threadIdx.x;
  if (tid < CIN * HD1) {
    int k = tid / HD1, n = tid % HD1;
    W1t[n * CIN + k] = (bf16_t)W1[tid];
  }
  if (tid < HD1 * HD2) {
    int k = tid / HD2, n = tid % HD2;
    W2t[n * HD1 + k] = (bf16_t)W2[tid];
  }
  if (tid < BDIM * N2) {
    const float* s = xyz2 + (size_t)tid * 3;
    float x = s[0], y = s[1], z = s[2];
    float4 v; v.x = x; v.y = y; v.z = z; v.w = x * x + y * y + z * z;
    xyzr[tid] = v;
  }
}

// ---- full-scan 3-NN with branchy threshold pruning ----
// Fast path per candidate: dt = r2 - 2*dot(xi,xj) via 3 FMAs (same order as
// exact d since |xi|^2 is query-constant). Exact path (validated insert
// network, bit-identical __fsub/__fmul/__fadd arithmetic) runs only when
// dt <= (d2 - |xi|^2) + 1e-3.  Margin analysis: |dt - (d_ref - r1)| <= 6e-5
// (partials <= ~130, <= 8 roundings) << 1e-3, so no true top-3 member is ever
// filtered; spurious eps-window survivors are rejected by the exact d < d2
// gate -> selection bit-identical to the fp32 reference (ties -> earlier j,
// ascending scan).  Expected wave-any-taken fraction ~19% over 4096.
// 256 blocks x 4 waves = 1 wave/SIMD: latency hidden by SGPR double-buffered
// 8-point groups (2x32 SGPR; the old c[48] scheme left no SGPR room to
// prefetch). Writes wq/iq directly: knn_merge kernel eliminated.
__global__ __launch_bounds__(256) void knn2(
    const float* __restrict__ xyz1, const float4* __restrict__ xyzr,
    float* __restrict__ wq, int* __restrict__ iq) {
  int b = blockIdx.y;
  int i = blockIdx.x * 256 + threadIdx.x;
  const float* p = xyz1 + ((size_t)b * N1 + i) * 3;
  float px = p[0], py = p[1], pz = p[2];
  float qx = -2.0f * px, qy = -2.0f * py, qz = -2.0f * pz;
  float r1 = px * px + py * py + pz * pz;
  const float4* base = xyzr + (size_t)b * N2;

  float d0 = 3.4e38f, d1 = 3.4e38f, d2 = 3.4e38f;
  int   j0 = 0, j1 = 0, j2 = 0;
  float thr = 3.4e38f;

  auto proc8 = [&](const float4* cb, int g) {
#pragma unroll
    for (int u = 0; u < 8; ++u) {
      float4 c = cb[u];
      float dt = __builtin_fmaf(qx, c.x, c.w);
      dt = __builtin_fmaf(qy, c.y, dt);
      dt = __builtin_fmaf(qz, c.z, dt);
      if (dt <= thr) {
        float dx = __fsub_rn(c.x, px);
        float dy = __fsub_rn(c.y, py);
        float dz = __fsub_rn(c.z, pz);
        float d = __fadd_rn(__fadd_rn(__fmul_rn(dx, dx), __fmul_rn(dy, dy)),
                            __fmul_rn(dz, dz));
        int jj = g + u;
        if (d < d2) {  // strict <: earlier index wins ties (matches top_k)
          bool lt0 = d < d0, lt1 = d < d1;
          j2 = lt1 ? j1 : jj;
          j1 = lt0 ? j0 : (lt1 ? jj : j1);
          j0 = lt0 ? jj : j0;
          d2 = __builtin_amdgcn_fmed3f(d, d1, d2);
          d1 = __builtin_amdgcn_fmed3f(d, d0, d1);
          d0 = fminf(d, d0);
          thr = __fadd_rn(__fsub_rn(d2, r1), 1e-3f);
        }
      }
    }
  };

  // software pipeline: two 8-point SGPR buffers, prefetch one phase ahead.
  // xyzr is padded by 16 entries past B*N2 so tail prefetches stay in-bounds.
  float4 A[8], Bv[8];
#pragma unroll
  for (int t = 0; t < 8; ++t) A[t] = base[t];
#pragma unroll
  for (int t = 0; t < 8; ++t) Bv[t] = base[8 + t];
  for (int g = 0; g < N2; g += 16) {
    proc8(A, g);
#pragma unroll
    for (int t = 0; t < 8; ++t) A[t] = base[g + 16 + t];
    proc8(Bv, g + 8);
#pragma unroll
    for (int t = 0; t < 8; ++t) Bv[t] = base[g + 24 + t];
  }

  // finalize (verbatim from validated knn_merge tail)
  d0 = fmaxf(d0, 1e-10f); d1 = fmaxf(d1, 1e-10f); d2 = fmaxf(d2, 1e-10f);
  float w0 = 1.0f / d0, w1 = 1.0f / d1, w2 = 1.0f / d2;
  float ws = w0 + w1 + w2;
  size_t q = (size_t)b * N1 + i;
  wq[q * 3 + 0] = w0 / ws; wq[q * 3 + 1] = w1 / ws; wq[q * 3 + 2] = w2 / ws;
  iq[q * 3 + 0] = j0; iq[q * 3 + 1] = j1; iq[q * 3 + 2] = j2;
}

// ---- FUSED interp+concat+GEMM1 (unchanged from validated R1 kernel) ----
__global__ __launch_bounds__(256, 2) void interp_gemm1(
    const float* __restrict__ f1, const float* __restrict__ f2,
    const float* __restrict__ wq, const int* __restrict__ iq,
    const bf16_t* __restrict__ W1t, const float* __restrict__ b1,
    bf16_t* __restrict__ Hbuf) {
  __shared__ __align__(16) bf16_t As[128 * 32];      // 8 KB  [row][32k]
  __shared__ __align__(16) bf16_t Bs[4 * 256 * 8];   // 16 KB [quad][n][8k]
  int tid  = threadIdx.x;
  int wv   = tid >> 6, ln = tid & 63;
  int quad = ln >> 4, lm = ln & 15;
  long row0 = (long)blockIdx.x * 128;

  int srow = tid >> 1;
  int sh   = tid & 1;
  long q = row0 + srow;
  int  b = (int)(q >> 14);  // N1 = 2^14
  float u0 = wq[q * 3 + 0], u1 = wq[q * 3 + 1], u2 = wq[q * 3 + 2];
  const float* f2b = f2 + (size_t)b * N2 * C2;
  const float* r0 = f2b + (size_t)iq[q * 3 + 0] * C2;
  const float* r1 = f2b + (size_t)iq[q * 3 + 1] * C2;
  const float* r2 = f2b + (size_t)iq[q * 3 + 2] * C2;
  const float* f1r = f1 + (size_t)q * C1;
  bf16_t* asd = As + srow * 32 + sh * 16;

  int wm = (wv >> 1) * 64, wn = (wv & 1) * 128;
  f32x4 acc[4][8] = {};

  for (int ks = 0; ks < 12; ++ks) {
    int kb = ks * 32;
#pragma unroll
    for (int s = 0; s < 4; ++s) {
      __builtin_amdgcn_global_load_lds(
          (const __attribute__((address_space(1))) void*)(
              W1t + (size_t)(wv * 64 + ln) * CIN + kb + s * 8),
          (__attribute__((address_space(3))) void*)(Bs + s * 2048 + wv * 512),
          16, 0, 0);
    }
    bf16x8 o[2];
    if (ks < 8) {
      int cb = kb + sh * 16;
#pragma unroll
      for (int c4 = 0; c4 < 4; ++c4) {
        float4 v0 = *(const float4*)(r0 + cb + c4 * 4);
        float4 v1 = *(const float4*)(r1 + cb + c4 * 4);
        float4 v2 = *(const float4*)(r2 + cb + c4 * 4);
        int oi = c4 >> 1, off = (c4 & 1) * 4;
        o[oi][off + 0] = (bf16_t)(u0 * v0.x + u1 * v1.x + u2 * v2.x);
        o[oi][off + 1] = (bf16_t)(u0 * v0.y + u1 * v1.y + u2 * v2.y);
        o[oi][off + 2] = (bf16_t)(u0 * v0.z + u1 * v1.z + u2 * v2.z);
        o[oi][off + 3] = (bf16_t)(u0 * v0.w + u1 * v1.w + u2 * v2.w);
      }
    } else {
      int cf = kb - 256 + sh * 16;
#pragma unroll
      for (int c4 = 0; c4 < 4; ++c4) {
        float4 g = *(const float4*)(f1r + cf + c4 * 4);
        int oi = c4 >> 1, off = (c4 & 1) * 4;
        o[oi][off + 0] = (bf16_t)g.x;
        o[oi][off + 1] = (bf16_t)g.y;
        o[oi][off + 2] = (bf16_t)g.z;
        o[oi][off + 3] = (bf16_t)g.w;
      }
    }
    *(bf16x8*)(asd) = o[0];
    *(bf16x8*)(asd + 8) = o[1];
    __syncthreads();

    bf16x8 af[4];
#pragma unroll
    for (int mi = 0; mi < 4; ++mi)
      af[mi] = *(const bf16x8*)(As + (wm + mi * 16 + lm) * 32 + quad * 8);
#pragma unroll
    for (int nh = 0; nh < 2; ++nh) {
      bf16x8 bfr[4];
#pragma unroll
      for (int nn = 0; nn < 4; ++nn)
        bfr[nn] = *(const bf16x8*)(Bs + quad * 2048 + (wn + (nh * 4 + nn) * 16 + lm) * 8);
#pragma unroll
      for (int mi = 0; mi < 4; ++mi)
#pragma unroll
        for (int nn = 0; nn < 4; ++nn)
          acc[mi][nh * 4 + nn] = __builtin_amdgcn_mfma_f32_16x16x32_bf16(
              af[mi], bfr[nn], acc[mi][nh * 4 + nn], 0, 0, 0);
    }
    __syncthreads();
  }

#pragma unroll
  for (int mi = 0; mi < 4; ++mi)
#pragma unroll
    for (int ni = 0; ni < 8; ++ni) {
      int col = wn + ni * 16 + lm;
      float bv = b1[col];
#pragma unroll
      for (int r = 0; r < 4; ++r) {
        long rowg = row0 + wm + mi * 16 + quad * 4 + r;
        float v = acc[mi][ni][r] + bv;
        v = fmaxf(v, 0.0f);
        Hbuf[rowg * HD1 + col] = (bf16_t)v;
      }
    }
}

// ---- bf16 MFMA GEMM (validated): C = relu(A @ Bt^T + bias) ----
template <bool OUT_BF16>
__global__ __launch_bounds__(256) void gemm_bt(
    const bf16_t* __restrict__ A, const bf16_t* __restrict__ Bt,
    const float* __restrict__ bias, void* __restrict__ Cout,
    int M, int N, int K) {
  __shared__ __align__(16) bf16_t As[128 * 32];
  __shared__ __align__(16) bf16_t Bs[128 * 32];
  int tid  = threadIdx.x;
  int wv   = tid >> 6, ln = tid & 63;
  int quad = ln >> 4, lm = ln & 15;
  long row0 = (long)blockIdx.x * 128;
  int  col0 = blockIdx.y * 128;
  const bf16_t* Ab = A + row0 * K;
  const bf16_t* Bb = Bt + (long)col0 * K;
  f32x4 acc[4][4] = {};
  int wm = (wv >> 1) * 64, wn = (wv & 1) * 64;

  for (int k0 = 0; k0 < K; k0 += 32) {
#pragma unroll
    for (int t = 0; t < 2; ++t) {
      int c = t * 256 + tid;
      int r = c >> 2, kc = (c & 3) << 3;
      __builtin_amdgcn_global_load_lds(
          (const __attribute__((address_space(1))) void*)(Ab + (long)r * K + k0 + kc),
          (__attribute__((address_space(3))) void*)(As + (t * 256 + wv * 64) * 8),
          16, 0, 0);
      __builtin_amdgcn_global_load_lds(
          (const __attribute__((address_space(1))) void*)(Bb + (long)r * K + k0 + kc),
          (__attribute__((address_space(3))) void*)(Bs + (t * 256 + wv * 64) * 8),
          16, 0, 0);
    }
    __syncthreads();
    bf16x8 af[4], bfr[4];
#pragma unroll
    for (int mi = 0; mi < 4; ++mi)
      af[mi] = *(const bf16x8*)(As + (wm + mi * 16 + lm) * 32 + quad * 8);
#pragma unroll
    for (int ni = 0; ni < 4; ++ni)
      bfr[ni] = *(const bf16x8*)(Bs + (wn + ni * 16 + lm) * 32 + quad * 8);
#pragma unroll
    for (int mi = 0; mi < 4; ++mi)
#pragma unroll
      for (int ni = 0; ni < 4; ++ni)
        acc[mi][ni] = __builtin_amdgcn_mfma_f32_16x16x32_bf16(af[mi], bfr[ni],
                                                              acc[mi][ni], 0, 0, 0);
    __syncthreads();
  }

#pragma unroll
  for (int mi = 0; mi < 4; ++mi)
#pragma unroll
    for (int ni = 0; ni < 4; ++ni) {
      int col = col0 + wn + ni * 16 + lm;
      float bv = bias[col];
#pragma unroll
      for (int r = 0; r < 4; ++r) {
        long rowg = row0 + wm + mi * 16 + quad * 4 + r;
        float v = acc[mi][ni][r] + bv;
        v = fmaxf(v, 0.0f);
        if (OUT_BF16) ((bf16_t*)Cout)[rowg * N + col] = (bf16_t)v;
        else          ((float*)Cout)[rowg * N + col]  = v;
      }
    }
}

extern "C" void kernel_launch(void* const* d_in, const int* in_sizes, int n_in,
                              void* d_out, int out_size, void* d_ws, size_t ws_size,
                              hipStream_t stream) {
  const float* xyz1 = (const float*)d_in[0];
  const float* xyz2 = (const float*)d_in[1];
  const float* f1   = (const float*)d_in[2];
  const float* f2   = (const float*)d_in[3];
  const float* W1   = (const float*)d_in[4];
  const float* b1   = (const float*)d_in[5];
  const float* W2   = (const float*)d_in[6];
  const float* b2   = (const float*)d_in[7];
  float* out = (float*)d_out;

  const size_t NQ = (size_t)BDIM * N1;  // 65536
  char* ws = (char*)d_ws;
  bf16_t* W1t = (bf16_t*)ws;                         // 192 KB
  bf16_t* W2t = (bf16_t*)(ws + (256 << 10));         // 64 KB
  float*  wq  = (float*)(ws + (512 << 10));          // 768 KB
  int*    iq  = (int*)(ws + (1536 << 10));           // 768 KB
  float4* xyzr = (float4*)(ws + (2560 << 10));       // 256 KB + 256 B pad
  char*   hb  = ws + (2560 << 10) + NQ * CIN * 2;
  bf16_t* Hbuf  = (bf16_t*)hb;

  prep_w<<<dim3(384), dim3(256), 0, stream>>>(W1, W2, xyz2, W1t, W2t, xyzr);
  knn2<<<dim3(N1 / 256, BDIM), dim3(256), 0, stream>>>(xyz1, xyzr, wq, iq);
  interp_gemm1<<<dim3(NQ / 128), dim3(256), 0, stream>>>(
      f1, f2, wq, iq, W1t, b1, Hbuf);
  gemm_bt<false><<<dim3(NQ / 128, HD2 / 128), dim3(256), 0, stream>>>(
      Hbuf, W2t, b2, (void*)out, NQ, HD2, HD1);
}

// Round 3
// 261.726 us; speedup vs baseline: 1.4041x; 1.4041x over previous
//
#include <hip/hip_runtime.h>
#include <hip/hip_bf16.h>

typedef __bf16 bf16_t;
typedef __attribute__((ext_vector_type(8))) __bf16 bf16x8;
typedef __attribute__((ext_vector_type(4))) __bf16 bf16x4;
typedef __attribute__((ext_vector_type(4))) float f32x4;

#define N1 16384
#define N2 4096
#define C1 128
#define C2 256
#define CIN 384
#define HD1 256
#define HD2 128
#define BDIM 4
#define CHUNK 1024
#define NCHUNK 4   // N2 / CHUNK
#define NCAND 12   // NCHUNK * 3

// ---- prep: weights -> bf16 [N][K]; pack xyz2 -> [x,y,z,|p|^2] ----
__global__ void prep_w(const float* __restrict__ W1, const float* __restrict__ W2,
                       const float* __restrict__ xyz2,
                       bf16_t* __restrict__ W1t, bf16_t* __restrict__ W2t,
                       float4* __restrict__ xyzr) {
  int tid = blockIdx.x * 256 + threadIdx.x;
  if (tid < CIN * HD1) {
    int k = tid / HD1, n = tid % HD1;
    W1t[n * CIN + k] = (bf16_t)W1[tid];
  }
  if (tid < HD1 * HD2) {
    int k = tid / HD2, n = tid % HD2;
    W2t[n * HD1 + k] = (bf16_t)W2[tid];
  }
  if (tid < BDIM * N2) {
    const float* s = xyz2 + (size_t)tid * 3;
    float x = s[0], y = s[1], z = s[2];
    float4 v; v.x = x; v.y = y; v.z = z; v.w = x * x + y * y + z * z;
    xyzr[tid] = v;
  }
}

// ---- chunked 3-NN, R1-validated skeleton + R2-validated pruning gate ----
// Structure = the 99.4us knn_chunk (group-of-16 wave-uniform s_loads, no hand
// pipelining) with CHUNK 512->1024 (NCHUNK 4): 1024 blocks = 16 waves/CU =
// 4/SIMD, the occupancy the R1(90% VALUBusy @8/SIMD) / R2(25% @1/SIMD) pair
// brackets as sufficient. Fast path per candidate (5 VALU): dt = r2 -
// 2*dot(xi,xj) via 3 FMAs; exact path (validated insert network, bit-exact
// __fsub/__fmul/__fadd) only when dt <= (d2 - |xi|^2) + 1e-3. Margin: |dt -
// (d_ref - r1)| <= 6e-5 << 1e-3 -> no true top-3 member filtered; spurious
// eps-window survivors rejected by exact d < d2 -> selection bit-identical
// (R2 passed end-to-end with this gate). Expected wave-taken fraction @1024
// ~0.42 -> ~13.4 VALU/cand vs 21.8 measured before.
__global__ __launch_bounds__(256) void knn_chunk3(
    const float* __restrict__ xyz1, const float4* __restrict__ xyzr,
    float* __restrict__ candd, int* __restrict__ candj) {
  int b  = blockIdx.y;
  int ck = blockIdx.z;
  int i  = blockIdx.x * 256 + threadIdx.x;
  const float* p = xyz1 + ((size_t)b * N1 + i) * 3;
  float px = p[0], py = p[1], pz = p[2];
  float qx = -2.0f * px, qy = -2.0f * py, qz = -2.0f * pz;
  float r1 = px * px + py * py + pz * pz;

  const float4* x2b = xyzr + (size_t)b * N2 + (size_t)ck * CHUNK;

  float d0 = 3.4e38f, d1 = 3.4e38f, d2 = 3.4e38f;
  int   j0 = 0, j1 = 0, j2 = 0;
  float thr = 3.4e38f;

  for (int j = 0; j < CHUNK; j += 16) {
    // 16 points = 16 float4 = 64 dwords, uniform addresses -> 4x s_load_dwordx16
    float4 c4[16];
#pragma unroll
    for (int t = 0; t < 16; ++t) c4[t] = x2b[j + t];
#pragma unroll
    for (int u = 0; u < 16; ++u) {
      float4 c = c4[u];
      float dt = __builtin_fmaf(qz, c.z, c.w);
      dt = __builtin_fmaf(qy, c.y, dt);
      dt = __builtin_fmaf(qx, c.x, dt);
      if (dt <= thr) {
        // exact distance, bit-identical ordering vs the fp32 reference
        float dx = __fsub_rn(c.x, px);
        float dy = __fsub_rn(c.y, py);
        float dz = __fsub_rn(c.z, pz);
        float d = __fadd_rn(__fadd_rn(__fmul_rn(dx, dx), __fmul_rn(dy, dy)),
                            __fmul_rn(dz, dz));
        int jj = j + u;
        if (d < d2) {  // strict <: earlier index wins ties (matches top_k)
          bool lt0 = d < d0, lt1 = d < d1;
          j2 = lt1 ? j1 : jj;
          j1 = lt0 ? j0 : (lt1 ? jj : j1);
          j0 = lt0 ? jj : j0;
          d2 = __builtin_amdgcn_fmed3f(d, d1, d2);
          d1 = __builtin_amdgcn_fmed3f(d, d0, d1);
          d0 = fminf(d, d0);
          thr = __fadd_rn(__fsub_rn(d2, r1), 1e-3f);
        }
      }
    }
  }
  size_t qb = ((size_t)b * N1 + i) * NCAND + (size_t)ck * 3;
  int jbase = ck * CHUNK;
  candd[qb + 0] = d0; candd[qb + 1] = d1; candd[qb + 2] = d2;
  candj[qb + 0] = j0 + jbase; candj[qb + 1] = j1 + jbase; candj[qb + 2] = j2 + jbase;
}

// ---- merge 4x3 candidates -> final top-3 + normalized weights ----
__global__ __launch_bounds__(256) void knn_merge(
    const float* __restrict__ candd, const int* __restrict__ candj,
    float* __restrict__ wq, int* __restrict__ iq) {
  int q = blockIdx.x * 256 + threadIdx.x;
  const float* cd = candd + (size_t)q * NCAND;
  const int*   cj = candj + (size_t)q * NCAND;
  float d0 = 3.4e38f, d1 = 3.4e38f, d2 = 3.4e38f;
  int   j0 = 0, j1 = 0, j2 = 0;
  // chunk-major, within-chunk sorted ascending: strict < keeps earliest j on ties
#pragma unroll
  for (int c = 0; c < NCAND; ++c) {
    float d = cd[c]; int j = cj[c];
    bool p0 = d < d0, p1 = d < d1, p2 = d < d2;
    j2 = p1 ? j1 : (p2 ? j : j2);
    j1 = p0 ? j0 : (p1 ? j : j1);
    j0 = p0 ? j : j0;
    d2 = __builtin_amdgcn_fmed3f(d, d1, d2);
    d1 = __builtin_amdgcn_fmed3f(d, d0, d1);
    d0 = fminf(d, d0);
  }
  d0 = fmaxf(d0, 1e-10f); d1 = fmaxf(d1, 1e-10f); d2 = fmaxf(d2, 1e-10f);
  float w0 = 1.0f / d0, w1 = 1.0f / d1, w2 = 1.0f / d2;
  float ws = w0 + w1 + w2;
  wq[q * 3 + 0] = w0 / ws; wq[q * 3 + 1] = w1 / ws; wq[q * 3 + 2] = w2 / ws;
  iq[q * 3 + 0] = j0; iq[q * 3 + 1] = j1; iq[q * 3 + 2] = j2;
}

// ---- FUSED interp+concat+GEMM1 (unchanged from validated R1 kernel) ----
__global__ __launch_bounds__(256, 2) void interp_gemm1(
    const float* __restrict__ f1, const float* __restrict__ f2,
    const float* __restrict__ wq, const int* __restrict__ iq,
    const bf16_t* __restrict__ W1t, const float* __restrict__ b1,
    bf16_t* __restrict__ Hbuf) {
  __shared__ __align__(16) bf16_t As[128 * 32];      // 8 KB  [row][32k]
  __shared__ __align__(16) bf16_t Bs[4 * 256 * 8];   // 16 KB [quad][n][8k]
  int tid  = threadIdx.x;
  int wv   = tid >> 6, ln = tid & 63;
  int quad = ln >> 4, lm = ln & 15;
  long row0 = (long)blockIdx.x * 128;

  int srow = tid >> 1;
  int sh   = tid & 1;
  long q = row0 + srow;
  int  b = (int)(q >> 14);  // N1 = 2^14
  float u0 = wq[q * 3 + 0], u1 = wq[q * 3 + 1], u2 = wq[q * 3 + 2];
  const float* f2b = f2 + (size_t)b * N2 * C2;
  const float* r0 = f2b + (size_t)iq[q * 3 + 0] * C2;
  const float* r1 = f2b + (size_t)iq[q * 3 + 1] * C2;
  const float* r2 = f2b + (size_t)iq[q * 3 + 2] * C2;
  const float* f1r = f1 + (size_t)q * C1;
  bf16_t* asd = As + srow * 32 + sh * 16;

  int wm = (wv >> 1) * 64, wn = (wv & 1) * 128;
  f32x4 acc[4][8] = {};

  for (int ks = 0; ks < 12; ++ks) {
    int kb = ks * 32;
#pragma unroll
    for (int s = 0; s < 4; ++s) {
      __builtin_amdgcn_global_load_lds(
          (const __attribute__((address_space(1))) void*)(
              W1t + (size_t)(wv * 64 + ln) * CIN + kb + s * 8),
          (__attribute__((address_space(3))) void*)(Bs + s * 2048 + wv * 512),
          16, 0, 0);
    }
    bf16x8 o[2];
    if (ks < 8) {
      int cb = kb + sh * 16;
#pragma unroll
      for (int c4 = 0; c4 < 4; ++c4) {
        float4 v0 = *(const float4*)(r0 + cb + c4 * 4);
        float4 v1 = *(const float4*)(r1 + cb + c4 * 4);
        float4 v2 = *(const float4*)(r2 + cb + c4 * 4);
        int oi = c4 >> 1, off = (c4 & 1) * 4;
        o[oi][off + 0] = (bf16_t)(u0 * v0.x + u1 * v1.x + u2 * v2.x);
        o[oi][off + 1] = (bf16_t)(u0 * v0.y + u1 * v1.y + u2 * v2.y);
        o[oi][off + 2] = (bf16_t)(u0 * v0.z + u1 * v1.z + u2 * v2.z);
        o[oi][off + 3] = (bf16_t)(u0 * v0.w + u1 * v1.w + u2 * v2.w);
      }
    } else {
      int cf = kb - 256 + sh * 16;
#pragma unroll
      for (int c4 = 0; c4 < 4; ++c4) {
        float4 g = *(const float4*)(f1r + cf + c4 * 4);
        int oi = c4 >> 1, off = (c4 & 1) * 4;
        o[oi][off + 0] = (bf16_t)g.x;
        o[oi][off + 1] = (bf16_t)g.y;
        o[oi][off + 2] = (bf16_t)g.z;
        o[oi][off + 3] = (bf16_t)g.w;
      }
    }
    *(bf16x8*)(asd) = o[0];
    *(bf16x8*)(asd + 8) = o[1];
    __syncthreads();

    bf16x8 af[4];
#pragma unroll
    for (int mi = 0; mi < 4; ++mi)
      af[mi] = *(const bf16x8*)(As + (wm + mi * 16 + lm) * 32 + quad * 8);
#pragma unroll
    for (int nh = 0; nh < 2; ++nh) {
      bf16x8 bfr[4];
#pragma unroll
      for (int nn = 0; nn < 4; ++nn)
        bfr[nn] = *(const bf16x8*)(Bs + quad * 2048 + (wn + (nh * 4 + nn) * 16 + lm) * 8);
#pragma unroll
      for (int mi = 0; mi < 4; ++mi)
#pragma unroll
        for (int nn = 0; nn < 4; ++nn)
          acc[mi][nh * 4 + nn] = __builtin_amdgcn_mfma_f32_16x16x32_bf16(
              af[mi], bfr[nn], acc[mi][nh * 4 + nn], 0, 0, 0);
    }
    __syncthreads();
  }

#pragma unroll
  for (int mi = 0; mi < 4; ++mi)
#pragma unroll
    for (int ni = 0; ni < 8; ++ni) {
      int col = wn + ni * 16 + lm;
      float bv = b1[col];
#pragma unroll
      for (int r = 0; r < 4; ++r) {
        long rowg = row0 + wm + mi * 16 + quad * 4 + r;
        float v = acc[mi][ni][r] + bv;
        v = fmaxf(v, 0.0f);
        Hbuf[rowg * HD1 + col] = (bf16_t)v;
      }
    }
}

// ---- bf16 MFMA GEMM (validated): C = relu(A @ Bt^T + bias) ----
template <bool OUT_BF16>
__global__ __launch_bounds__(256) void gemm_bt(
    const bf16_t* __restrict__ A, const bf16_t* __restrict__ Bt,
    const float* __restrict__ bias, void* __restrict__ Cout,
    int M, int N, int K) {
  __shared__ __align__(16) bf16_t As[128 * 32];
  __shared__ __align__(16) bf16_t Bs[128 * 32];
  int tid  = threadIdx.x;
  int wv   = tid >> 6, ln = tid & 63;
  int quad = ln >> 4, lm = ln & 15;
  long row0 = (long)blockIdx.x * 128;
  int  col0 = blockIdx.y * 128;
  const bf16_t* Ab = A + row0 * K;
  const bf16_t* Bb = Bt + (long)col0 * K;
  f32x4 acc[4][4] = {};
  int wm = (wv >> 1) * 64, wn = (wv & 1) * 64;

  for (int k0 = 0; k0 < K; k0 += 32) {
#pragma unroll
    for (int t = 0; t < 2; ++t) {
      int c = t * 256 + tid;
      int r = c >> 2, kc = (c & 3) << 3;
      __builtin_amdgcn_global_load_lds(
          (const __attribute__((address_space(1))) void*)(Ab + (long)r * K + k0 + kc),
          (__attribute__((address_space(3))) void*)(As + (t * 256 + wv * 64) * 8),
          16, 0, 0);
      __builtin_amdgcn_global_load_lds(
          (const __attribute__((address_space(1))) void*)(Bb + (long)r * K + k0 + kc),
          (__attribute__((address_space(3))) void*)(Bs + (t * 256 + wv * 64) * 8),
          16, 0, 0);
    }
    __syncthreads();
    bf16x8 af[4], bfr[4];
#pragma unroll
    for (int mi = 0; mi < 4; ++mi)
      af[mi] = *(const bf16x8*)(As + (wm + mi * 16 + lm) * 32 + quad * 8);
#pragma unroll
    for (int ni = 0; ni < 4; ++ni)
      bfr[ni] = *(const bf16x8*)(Bs + (wn + ni * 16 + lm) * 32 + quad * 8);
#pragma unroll
    for (int mi = 0; mi < 4; ++mi)
#pragma unroll
      for (int ni = 0; ni < 4; ++ni)
        acc[mi][ni] = __builtin_amdgcn_mfma_f32_16x16x32_bf16(af[mi], bfr[ni],
                                                              acc[mi][ni], 0, 0, 0);
    __syncthreads();
  }

#pragma unroll
  for (int mi = 0; mi < 4; ++mi)
#pragma unroll
    for (int ni = 0; ni < 4; ++ni) {
      int col = col0 + wn + ni * 16 + lm;
      float bv = bias[col];
#pragma unroll
      for (int r = 0; r < 4; ++r) {
        long rowg = row0 + wm + mi * 16 + quad * 4 + r;
        float v = acc[mi][ni][r] + bv;
        v = fmaxf(v, 0.0f);
        if (OUT_BF16) ((bf16_t*)Cout)[rowg * N + col] = (bf16_t)v;
        else          ((float*)Cout)[rowg * N + col]  = v;
      }
    }
}

extern "C" void kernel_launch(void* const* d_in, const int* in_sizes, int n_in,
                              void* d_out, int out_size, void* d_ws, size_t ws_size,
                              hipStream_t stream) {
  const float* xyz1 = (const float*)d_in[0];
  const float* xyz2 = (const float*)d_in[1];
  const float* f1   = (const float*)d_in[2];
  const float* f2   = (const float*)d_in[3];
  const float* W1   = (const float*)d_in[4];
  const float* b1   = (const float*)d_in[5];
  const float* W2   = (const float*)d_in[6];
  const float* b2   = (const float*)d_in[7];
  float* out = (float*)d_out;

  const size_t NQ = (size_t)BDIM * N1;  // 65536
  char* ws = (char*)d_ws;
  bf16_t* W1t = (bf16_t*)ws;                         // 192 KB
  bf16_t* W2t = (bf16_t*)(ws + (256 << 10));         // 64 KB
  float*  wq  = (float*)(ws + (512 << 10));          // 768 KB
  int*    iq  = (int*)(ws + (1536 << 10));           // 768 KB
  float4* xyzr = (float4*)(ws + (2560 << 10));       // 256 KB
  char*   hb  = ws + (2560 << 10) + NQ * CIN * 2;
  bf16_t* Hbuf  = (bf16_t*)hb;
  // candidates alias Hbuf (consumed by merge before interp_gemm1 writes Hbuf)
  float*  candd = (float*)hb;                        // 3.1 MB
  int*    candj = (int*)(hb + NQ * NCAND * 4);       // 3.1 MB

  prep_w<<<dim3(384), dim3(256), 0, stream>>>(W1, W2, xyz2, W1t, W2t, xyzr);
  knn_chunk3<<<dim3(N1 / 256, BDIM, NCHUNK), dim3(256), 0, stream>>>(
      xyz1, xyzr, candd, candj);
  knn_merge<<<dim3(NQ / 256), dim3(256), 0, stream>>>(candd, candj, wq, iq);
  interp_gemm1<<<dim3(NQ / 128), dim3(256), 0, stream>>>(
      f1, f2, wq, iq, W1t, b1, Hbuf);
  gemm_bt<false><<<dim3(NQ / 128, HD2 / 128), dim3(256), 0, stream>>>(
      Hbuf, W2t, b2, (void*)out, NQ, HD2, HD1);
}

// Round 4
// 244.845 us; speedup vs baseline: 1.5009x; 1.0689x over previous
//
#include <hip/hip_runtime.h>
#include <hip/hip_bf16.h>

typedef __bf16 bf16_t;
typedef __attribute__((ext_vector_type(8))) __bf16 bf16x8;
typedef __attribute__((ext_vector_type(4))) __bf16 bf16x4;
typedef __attribute__((ext_vector_type(4))) float f32x4;

#define N1 16384
#define N2 4096
#define C1 128
#define C2 256
#define CIN 384
#define HD1 256
#define HD2 128
#define BDIM 4
#define CHUNK 512
#define NCHUNK 8   // N2 / CHUNK
#define NCAND 24   // NCHUNK * 3

// ---- prep: weights -> bf16 [N][K]; f2 -> bf16 (halves scattered gather bytes,
// shrinks slab 16.8->8.4 MB so per-XCD L2 hit rate ~doubles) ----
__global__ void prep_w(const float* __restrict__ W1, const float* __restrict__ W2,
                       const float* __restrict__ f2,
                       bf16_t* __restrict__ W1t, bf16_t* __restrict__ W2t,
                       bf16_t* __restrict__ f2bf) {
  int tid = blockIdx.x * 256 + threadIdx.x;
  if (tid < CIN * HD1) {
    int k = tid / HD1, n = tid % HD1;
    W1t[n * CIN + k] = (bf16_t)W1[tid];
  }
  if (tid < HD1 * HD2) {
    int k = tid / HD2, n = tid % HD2;
    W2t[n * HD1 + k] = (bf16_t)W2[tid];
  }
  // f2 cast: 8 floats per thread (BDIM*N2*C2 = 4.19M elements, grid 2048x256)
  const float4* s4 = (const float4*)f2;
  float4 a = s4[2 * (size_t)tid], b = s4[2 * (size_t)tid + 1];
  bf16x8 o;
  o[0] = (bf16_t)a.x; o[1] = (bf16_t)a.y; o[2] = (bf16_t)a.z; o[3] = (bf16_t)a.w;
  o[4] = (bf16_t)b.x; o[5] = (bf16_t)b.y; o[6] = (bf16_t)b.z; o[7] = (bf16_t)b.w;
  *(bf16x8*)(f2bf + (size_t)tid * 8) = o;
}

// ---- per-chunk top-3 (VALIDATED 99.4us R1 version, verbatim) ----
__global__ __launch_bounds__(256) void knn_chunk(
    const float* __restrict__ xyz1, const float* __restrict__ xyz2,
    float* __restrict__ candd, int* __restrict__ candj) {
  int b  = blockIdx.y;
  int ck = blockIdx.z;
  int i  = blockIdx.x * 256 + threadIdx.x;
  const float* p = xyz1 + ((size_t)b * N1 + i) * 3;
  float px = p[0], py = p[1], pz = p[2];

  const float* x2b = xyz2 + ((size_t)b * N2 + (size_t)ck * CHUNK) * 3;

  float d0 = 3.4e38f, d1 = 3.4e38f, d2 = 3.4e38f;
  int   j0 = 0, j1 = 0, j2 = 0;

  for (int j = 0; j < CHUNK; j += 16) {
    float c[48];
    const float4* q = (const float4*)(x2b + 3 * j);
#pragma unroll
    for (int t = 0; t < 12; ++t) {
      float4 v = q[t];
      c[4 * t + 0] = v.x; c[4 * t + 1] = v.y; c[4 * t + 2] = v.z; c[4 * t + 3] = v.w;
    }
#pragma unroll
    for (int u = 0; u < 16; ++u) {
      float dx = __fsub_rn(c[3 * u + 0], px);
      float dy = __fsub_rn(c[3 * u + 1], py);
      float dz = __fsub_rn(c[3 * u + 2], pz);
      float d = __fadd_rn(__fadd_rn(__fmul_rn(dx, dx), __fmul_rn(dy, dy)),
                          __fmul_rn(dz, dz));
      int jj = j + u;
      if (d < d2) {  // strict <: earlier index wins ties (matches top_k)
        bool lt0 = d < d0, lt1 = d < d1;
        j2 = lt1 ? j1 : jj;
        j1 = lt0 ? j0 : (lt1 ? jj : j1);
        j0 = lt0 ? jj : j0;
        d2 = __builtin_amdgcn_fmed3f(d, d1, d2);
        d1 = __builtin_amdgcn_fmed3f(d, d0, d1);
        d0 = fminf(d, d0);
      }
    }
  }
  size_t qb = ((size_t)b * N1 + i) * NCAND + (size_t)ck * 3;
  int jbase = ck * CHUNK;
  candd[qb + 0] = d0; candd[qb + 1] = d1; candd[qb + 2] = d2;
  candj[qb + 0] = j0 + jbase; candj[qb + 1] = j1 + jbase; candj[qb + 2] = j2 + jbase;
}

// ---- merge 8x3 candidates -> final top-3 + normalized weights ----
__global__ __launch_bounds__(256) void knn_merge(
    const float* __restrict__ candd, const int* __restrict__ candj,
    float* __restrict__ wq, int* __restrict__ iq) {
  int q = blockIdx.x * 256 + threadIdx.x;
  const float* cd = candd + (size_t)q * NCAND;
  const int*   cj = candj + (size_t)q * NCAND;
  float d0 = 3.4e38f, d1 = 3.4e38f, d2 = 3.4e38f;
  int   j0 = 0, j1 = 0, j2 = 0;
#pragma unroll
  for (int c = 0; c < NCAND; ++c) {
    float d = cd[c]; int j = cj[c];
    bool p0 = d < d0, p1 = d < d1, p2 = d < d2;
    j2 = p1 ? j1 : (p2 ? j : j2);
    j1 = p0 ? j0 : (p1 ? j : j1);
    j0 = p0 ? j : j0;
    d2 = __builtin_amdgcn_fmed3f(d, d1, d2);
    d1 = __builtin_amdgcn_fmed3f(d, d0, d1);
    d0 = fminf(d, d0);
  }
  d0 = fmaxf(d0, 1e-10f); d1 = fmaxf(d1, 1e-10f); d2 = fmaxf(d2, 1e-10f);
  float w0 = 1.0f / d0, w1 = 1.0f / d1, w2 = 1.0f / d2;
  float ws = w0 + w1 + w2;
  wq[q * 3 + 0] = w0 / ws; wq[q * 3 + 1] = w1 / ws; wq[q * 3 + 2] = w2 / ws;
  iq[q * 3 + 0] = j0; iq[q * 3 + 1] = j1; iq[q * 3 + 2] = j2;
}

// ---- FUSED interp+concat+GEMM1 with pipelined bf16 gather ----
// Delta vs R1-validated kernel: (1) f2 gather reads pre-cast bf16 (32 B/nbr/
// step, one 64B line per row-step for the thread pair); (2) gather for step
// ks+1 prefetched into registers right after the mid-step barrier, so load
// latency hides under the MFMA phase and the compiler's vmcnt(0)-before-
// barrier drain at step end completes it -> next convert never stalls.
// MFMA mapping / W1 staging / epilogue unchanged (validated).
__global__ __launch_bounds__(256, 2) void interp_gemm1(
    const float* __restrict__ f1, const bf16_t* __restrict__ f2b_,
    const float* __restrict__ wq, const int* __restrict__ iq,
    const bf16_t* __restrict__ W1t, const float* __restrict__ b1,
    bf16_t* __restrict__ Hbuf) {
  __shared__ __align__(16) bf16_t As[128 * 32];      // 8 KB  [row][32k]
  __shared__ __align__(16) bf16_t Bs[4 * 256 * 8];   // 16 KB [quad][n][8k]
  int tid  = threadIdx.x;
  int wv   = tid >> 6, ln = tid & 63;
  int quad = ln >> 4, lm = ln & 15;
  long row0 = (long)blockIdx.x * 128;

  int srow = tid >> 1;
  int sh   = tid & 1;
  long q = row0 + srow;
  int  b = (int)(q >> 14);  // N1 = 2^14
  float u0 = wq[q * 3 + 0], u1 = wq[q * 3 + 1], u2 = wq[q * 3 + 2];
  const bf16_t* f2bb = f2b_ + (size_t)b * N2 * C2;
  const bf16_t* r0 = f2bb + (size_t)iq[q * 3 + 0] * C2;
  const bf16_t* r1 = f2bb + (size_t)iq[q * 3 + 1] * C2;
  const bf16_t* r2 = f2bb + (size_t)iq[q * 3 + 2] * C2;
  const float* f1r = f1 + (size_t)q * C1;
  bf16_t* asd = As + srow * 32 + sh * 16;

  int wm = (wv >> 1) * 64, wn = (wv & 1) * 128;
  f32x4 acc[4][8] = {};

  // prefetch registers
  bf16x8 g0a, g0b, g1a, g1b, g2a, g2b;  // f2 path (ks<8): 16 cols x 3 nbrs
  float4 gf[4];                          // f1 path (ks>=8): 16 cols fp32
  {
    int cb = sh * 16;
    g0a = *(const bf16x8*)(r0 + cb); g0b = *(const bf16x8*)(r0 + cb + 8);
    g1a = *(const bf16x8*)(r1 + cb); g1b = *(const bf16x8*)(r1 + cb + 8);
    g2a = *(const bf16x8*)(r2 + cb); g2b = *(const bf16x8*)(r2 + cb + 8);
  }

  for (int ks = 0; ks < 12; ++ks) {
    int kb = ks * 32;
    // W1 stage (DMA; dest Bs free since previous step's trailing barrier)
#pragma unroll
    for (int s = 0; s < 4; ++s) {
      __builtin_amdgcn_global_load_lds(
          (const __attribute__((address_space(1))) void*)(
              W1t + (size_t)(wv * 64 + ln) * CIN + kb + s * 8),
          (__attribute__((address_space(3))) void*)(Bs + s * 2048 + wv * 512),
          16, 0, 0);
    }
    // convert prefetched data -> A-tile slab (16 bf16 cols)
    bf16x8 o[2];
    if (ks < 8) {
#pragma unroll
      for (int e = 0; e < 8; ++e) {
        o[0][e] = (bf16_t)(u0 * (float)g0a[e] + u1 * (float)g1a[e] +
                           u2 * (float)g2a[e]);
        o[1][e] = (bf16_t)(u0 * (float)g0b[e] + u1 * (float)g1b[e] +
                           u2 * (float)g2b[e]);
      }
    } else {
#pragma unroll
      for (int c4 = 0; c4 < 4; ++c4) {
        float4 g = gf[c4];
        int oi = c4 >> 1, off = (c4 & 1) * 4;
        o[oi][off + 0] = (bf16_t)g.x;
        o[oi][off + 1] = (bf16_t)g.y;
        o[oi][off + 2] = (bf16_t)g.z;
        o[oi][off + 3] = (bf16_t)g.w;
      }
    }
    *(bf16x8*)(asd) = o[0];
    *(bf16x8*)(asd + 8) = o[1];
    __syncthreads();

    // prefetch step ks+1 (in flight across the MFMA phase; drained by the
    // compiler's vmcnt(0) before the trailing barrier)
    if (ks < 7) {
      int cb = (ks + 1) * 32 + sh * 16;
      g0a = *(const bf16x8*)(r0 + cb); g0b = *(const bf16x8*)(r0 + cb + 8);
      g1a = *(const bf16x8*)(r1 + cb); g1b = *(const bf16x8*)(r1 + cb + 8);
      g2a = *(const bf16x8*)(r2 + cb); g2b = *(const bf16x8*)(r2 + cb + 8);
    } else if (ks < 11) {
      int cf = (ks - 7) * 32 + sh * 16;
#pragma unroll
      for (int c4 = 0; c4 < 4; ++c4)
        gf[c4] = *(const float4*)(f1r + cf + c4 * 4);
    }

    bf16x8 af[4];
#pragma unroll
    for (int mi = 0; mi < 4; ++mi)
      af[mi] = *(const bf16x8*)(As + (wm + mi * 16 + lm) * 32 + quad * 8);
#pragma unroll
    for (int nh = 0; nh < 2; ++nh) {
      bf16x8 bfr[4];
#pragma unroll
      for (int nn = 0; nn < 4; ++nn)
        bfr[nn] = *(const bf16x8*)(Bs + quad * 2048 + (wn + (nh * 4 + nn) * 16 + lm) * 8);
#pragma unroll
      for (int mi = 0; mi < 4; ++mi)
#pragma unroll
        for (int nn = 0; nn < 4; ++nn)
          acc[mi][nh * 4 + nn] = __builtin_amdgcn_mfma_f32_16x16x32_bf16(
              af[mi], bfr[nn], acc[mi][nh * 4 + nn], 0, 0, 0);
    }
    __syncthreads();
  }

#pragma unroll
  for (int mi = 0; mi < 4; ++mi)
#pragma unroll
    for (int ni = 0; ni < 8; ++ni) {
      int col = wn + ni * 16 + lm;
      float bv = b1[col];
#pragma unroll
      for (int r = 0; r < 4; ++r) {
        long rowg = row0 + wm + mi * 16 + quad * 4 + r;
        float v = acc[mi][ni][r] + bv;
        v = fmaxf(v, 0.0f);
        Hbuf[rowg * HD1 + col] = (bf16_t)v;
      }
    }
}

// ---- bf16 MFMA GEMM (validated): C = relu(A @ Bt^T + bias) ----
template <bool OUT_BF16>
__global__ __launch_bounds__(256) void gemm_bt(
    const bf16_t* __restrict__ A, const bf16_t* __restrict__ Bt,
    const float* __restrict__ bias, void* __restrict__ Cout,
    int M, int N, int K) {
  __shared__ __align__(16) bf16_t As[128 * 32];
  __shared__ __align__(16) bf16_t Bs[128 * 32];
  int tid  = threadIdx.x;
  int wv   = tid >> 6, ln = tid & 63;
  int quad = ln >> 4, lm = ln & 15;
  long row0 = (long)blockIdx.x * 128;
  int  col0 = blockIdx.y * 128;
  const bf16_t* Ab = A + row0 * K;
  const bf16_t* Bb = Bt + (long)col0 * K;
  f32x4 acc[4][4] = {};
  int wm = (wv >> 1) * 64, wn = (wv & 1) * 64;

  for (int k0 = 0; k0 < K; k0 += 32) {
#pragma unroll
    for (int t = 0; t < 2; ++t) {
      int c = t * 256 + tid;
      int r = c >> 2, kc = (c & 3) << 3;
      __builtin_amdgcn_global_load_lds(
          (const __attribute__((address_space(1))) void*)(Ab + (long)r * K + k0 + kc),
          (__attribute__((address_space(3))) void*)(As + (t * 256 + wv * 64) * 8),
          16, 0, 0);
      __builtin_amdgcn_global_load_lds(
          (const __attribute__((address_space(1))) void*)(Bb + (long)r * K + k0 + kc),
          (__attribute__((address_space(3))) void*)(Bs + (t * 256 + wv * 64) * 8),
          16, 0, 0);
    }
    __syncthreads();
    bf16x8 af[4], bfr[4];
#pragma unroll
    for (int mi = 0; mi < 4; ++mi)
      af[mi] = *(const bf16x8*)(As + (wm + mi * 16 + lm) * 32 + quad * 8);
#pragma unroll
    for (int ni = 0; ni < 4; ++ni)
      bfr[ni] = *(const bf16x8*)(Bs + (wn + ni * 16 + lm) * 32 + quad * 8);
#pragma unroll
    for (int mi = 0; mi < 4; ++mi)
#pragma unroll
      for (int ni = 0; ni < 4; ++ni)
        acc[mi][ni] = __builtin_amdgcn_mfma_f32_16x16x32_bf16(af[mi], bfr[ni],
                                                              acc[mi][ni], 0, 0, 0);
    __syncthreads();
  }

#pragma unroll
  for (int mi = 0; mi < 4; ++mi)
#pragma unroll
    for (int ni = 0; ni < 4; ++ni) {
      int col = col0 + wn + ni * 16 + lm;
      float bv = bias[col];
#pragma unroll
      for (int r = 0; r < 4; ++r) {
        long rowg = row0 + wm + mi * 16 + quad * 4 + r;
        float v = acc[mi][ni][r] + bv;
        v = fmaxf(v, 0.0f);
        if (OUT_BF16) ((bf16_t*)Cout)[rowg * N + col] = (bf16_t)v;
        else          ((float*)Cout)[rowg * N + col]  = v;
      }
    }
}

extern "C" void kernel_launch(void* const* d_in, const int* in_sizes, int n_in,
                              void* d_out, int out_size, void* d_ws, size_t ws_size,
                              hipStream_t stream) {
  const float* xyz1 = (const float*)d_in[0];
  const float* xyz2 = (const float*)d_in[1];
  const float* f1   = (const float*)d_in[2];
  const float* f2   = (const float*)d_in[3];
  const float* W1   = (const float*)d_in[4];
  const float* b1   = (const float*)d_in[5];
  const float* W2   = (const float*)d_in[6];
  const float* b2   = (const float*)d_in[7];
  float* out = (float*)d_out;

  const size_t NQ = (size_t)BDIM * N1;  // 65536
  char* ws = (char*)d_ws;
  bf16_t* W1t = (bf16_t*)ws;                         // 192 KB
  bf16_t* W2t = (bf16_t*)(ws + (256 << 10));         // 64 KB
  float*  wq  = (float*)(ws + (512 << 10));          // 768 KB
  int*    iq  = (int*)(ws + (1536 << 10));           // 768 KB
  bf16_t* f2bf = (bf16_t*)(ws + (2560 << 10));       // 8.4 MB (in old NF gap)
  char*   hb  = ws + (2560 << 10) + NQ * CIN * 2;
  bf16_t* Hbuf  = (bf16_t*)hb;
  // candidates alias Hbuf (consumed by merge before interp_gemm1 writes Hbuf)
  float*  candd = (float*)hb;                        // 6.3 MB
  int*    candj = (int*)(hb + NQ * NCAND * 4);       // 6.3 MB

  prep_w<<<dim3(2048), dim3(256), 0, stream>>>(W1, W2, f2, W1t, W2t, f2bf);
  knn_chunk<<<dim3(N1 / 256, BDIM, NCHUNK), dim3(256), 0, stream>>>(
      xyz1, xyz2, candd, candj);
  knn_merge<<<dim3(NQ / 256), dim3(256), 0, stream>>>(candd, candj, wq, iq);
  interp_gemm1<<<dim3(NQ / 128), dim3(256), 0, stream>>>(
      f1, f2bf, wq, iq, W1t, b1, Hbuf);
  gemm_bt<false><<<dim3(NQ / 128, HD2 / 128), dim3(256), 0, stream>>>(
      Hbuf, W2t, b2, (void*)out, NQ, HD2, HD1);
}